// Round 1
// baseline (1338.914 us; speedup 1.0000x reference)
//
#include <hip/hip_runtime.h>

#define N_NODES 100000
#define N_EDGES 3200000
#define N_GRAPHS 256
#define NODE_DIM 7
#define HID 64
#define NLAY 3
#define EPSV 1e-5f

// ---------------- graph-structure kernels (run once per call) ----------------

__global__ __launch_bounds__(256) void k_deg(const int* __restrict__ dst, int* __restrict__ degE) {
    int e = blockIdx.x * 256 + threadIdx.x;
    if (e < N_EDGES) atomicAdd(&degE[dst[e]], 1);
}

__global__ __launch_bounds__(256) void k_dinv(const int* __restrict__ degE, const int* __restrict__ batch,
                                              float* __restrict__ dinv, int* __restrict__ gcnt) {
    int v = blockIdx.x * 256 + threadIdx.x;
    if (v < N_NODES) {
        dinv[v] = rsqrtf((float)(degE[v] + 1));   // +1 self-loop; always > 0
        atomicAdd(&gcnt[batch[v]], 1);
    }
}

// inclusive scan of degE within 1024-blocks
__global__ __launch_bounds__(1024) void k_scan1(const int* __restrict__ degE, int* __restrict__ tmp,
                                                int* __restrict__ bsum) {
    __shared__ int sh[1024];
    int i = blockIdx.x * 1024 + threadIdx.x;
    int v = (i < N_NODES) ? degE[i] : 0;
    sh[threadIdx.x] = v;
    __syncthreads();
    for (int ofs = 1; ofs < 1024; ofs <<= 1) {
        int t = (threadIdx.x >= (unsigned)ofs) ? sh[threadIdx.x - ofs] : 0;
        __syncthreads();
        sh[threadIdx.x] += t;
        __syncthreads();
    }
    if (i < N_NODES) tmp[i] = sh[threadIdx.x];
    if (threadIdx.x == 1023) bsum[blockIdx.x] = sh[1023];
}

__global__ __launch_bounds__(128) void k_scan2(int* __restrict__ bsum, int nb) {
    __shared__ int sh[128];
    int t = threadIdx.x;
    int v = (t < nb) ? bsum[t] : 0;
    sh[t] = v;
    __syncthreads();
    for (int ofs = 1; ofs < 128; ofs <<= 1) {
        int u = (t >= ofs) ? sh[t - ofs] : 0;
        __syncthreads();
        sh[t] += u;
        __syncthreads();
    }
    if (t < nb) bsum[t] = sh[t] - v;   // exclusive block offsets
}

__global__ __launch_bounds__(256) void k_scan3(const int* __restrict__ tmp, const int* __restrict__ bsum,
                                               int* __restrict__ rowptr) {
    int i = blockIdx.x * 256 + threadIdx.x;
    if (i < N_NODES) rowptr[i + 1] = tmp[i] + bsum[i >> 10];
    if (i == 0) rowptr[0] = 0;
}

__global__ __launch_bounds__(256) void k_fill(const int* __restrict__ src, const int* __restrict__ dst,
                                              const int* __restrict__ rowptr, int* __restrict__ cursor,
                                              int* __restrict__ cols) {
    int e = blockIdx.x * 256 + threadIdx.x;
    if (e < N_EDGES) {
        int d = dst[e];
        int pos = rowptr[d] + atomicAdd(&cursor[d], 1);
        cols[pos] = src[e];
    }
}

// ---------------- per-layer kernels ----------------

// h0 = x @ Win + bin
__global__ __launch_bounds__(256) void k_h0(const float* __restrict__ x, const float* __restrict__ Win,
                                            const float* __restrict__ b, float* __restrict__ h) {
    int i = blockIdx.x * 256 + threadIdx.x;
    if (i >= N_NODES * HID) return;
    int v = i >> 6, j = i & 63;
    float acc = b[j];
#pragma unroll
    for (int k = 0; k < NODE_DIM; k++) acc += x[v * NODE_DIM + k] * Win[k * HID + j];
    h[i] = acc;
}

// y = (h @ W) * dinv[:,None] ; 64 nodes per block, LDS-staged tiles
__global__ __launch_bounds__(256) void k_xw(const float* __restrict__ h, const float* __restrict__ W,
                                            const float* __restrict__ dinv, float* __restrict__ y) {
    __shared__ float Ws[HID][HID];
    __shared__ float Hs[64][HID];
    int t = threadIdx.x;
    int nb = blockIdx.x * 64;
#pragma unroll
    for (int k = 0; k < 16; k++) {
        int idx = t + k * 256;
        Ws[idx >> 6][idx & 63] = W[idx];
        int r = idx >> 6, cc = idx & 63;
        int node = nb + r;
        Hs[r][cc] = (node < N_NODES) ? h[(size_t)node * HID + cc] : 0.f;
    }
    __syncthreads();
    int j = t & 63;
    int r0 = t >> 6;          // wave-uniform (0..3)
    for (int rr = r0; rr < 64; rr += 4) {
        int node = nb + rr;
        if (node >= N_NODES) continue;
        float acc = 0.f;
#pragma unroll
        for (int k = 0; k < HID; k++) acc += Hs[rr][k] * Ws[k][j];
        y[(size_t)node * HID + j] = acc * dinv[node];
    }
}

// c[v] = dinv[v]*(y[v] + sum_{in-edges} y[s]) + bias ; fused per-graph S1/S2 stats
__global__ __launch_bounds__(256) void k_agg(const float* __restrict__ y, const int* __restrict__ rowptr,
                                             const int* __restrict__ cols, const float* __restrict__ dinv,
                                             const float* __restrict__ bias, const int* __restrict__ batch,
                                             float* __restrict__ c, float* __restrict__ gS1,
                                             float* __restrict__ gS2) {
    int wid = (blockIdx.x * 256 + threadIdx.x) >> 6;   // one wave per node
    int lane = threadIdx.x & 63;
    if (wid >= N_NODES) return;
    int v = wid;
    float acc = y[(size_t)v * HID + lane];
    int e0 = rowptr[v], e1 = rowptr[v + 1];
    float a0 = 0.f, a1 = 0.f, a2 = 0.f, a3 = 0.f;
    int e = e0;
    for (; e + 3 < e1; e += 4) {
        int s0 = cols[e], s1 = cols[e + 1], s2 = cols[e + 2], s3 = cols[e + 3];
        a0 += y[(size_t)s0 * HID + lane];
        a1 += y[(size_t)s1 * HID + lane];
        a2 += y[(size_t)s2 * HID + lane];
        a3 += y[(size_t)s3 * HID + lane];
    }
    for (; e < e1; ++e) a0 += y[(size_t)cols[e] * HID + lane];
    acc += (a0 + a1) + (a2 + a3);
    float cv = dinv[v] * acc + bias[lane];
    c[(size_t)v * HID + lane] = cv;
    int g = batch[v];
    atomicAdd(&gS1[g * HID + lane], cv);
    atomicAdd(&gS2[g * HID + lane], cv * cv);
}

// per-graph mean / inv-std.  var = S2/cnt - 2*s*m^2 + s^2*m^2
__global__ __launch_bounds__(256) void k_stats(const float* __restrict__ gS1, const float* __restrict__ gS2,
                                               const int* __restrict__ gcnt, const float* __restrict__ gnS_l,
                                               float* __restrict__ gmean, float* __restrict__ ginv) {
    int i = blockIdx.x * 256 + threadIdx.x;
    if (i >= N_GRAPHS * HID) return;
    int g = i >> 6, j = i & 63;
    float cnt = fmaxf((float)gcnt[g], 1.f);
    float m = gS1[i] / cnt;
    float s = gnS_l[j];
    float var = gS2[i] / cnt - 2.f * s * m * m + s * s * m * m;
    gmean[i] = m;
    ginv[i] = rsqrtf(var + EPSV);
}

// h += relu(gnW*(c - s*mean)*invstd + gnB) ; optionally accumulate graph-emb sums
__global__ __launch_bounds__(256) void k_update(const float* __restrict__ c, const int* __restrict__ batch,
                                                const float* __restrict__ gmean, const float* __restrict__ ginv,
                                                const float* __restrict__ gnW_l, const float* __restrict__ gnB_l,
                                                const float* __restrict__ gnS_l, float* __restrict__ h,
                                                float* __restrict__ gemb, int accum_emb) {
    int i = blockIdx.x * 256 + threadIdx.x;
    if (i >= N_NODES * HID) return;
    int v = i >> 6, j = i & 63;
    int g = batch[v];
    float outv = c[i] - gnS_l[j] * gmean[g * HID + j];
    float val = gnW_l[j] * outv * ginv[g * HID + j] + gnB_l[j];
    float hn = h[i] + fmaxf(val, 0.f);
    h[i] = hn;
    if (accum_emb) atomicAdd(&gemb[g * HID + j], hn);
}

// classifier head: emb = gemb/cnt ; z = relu(emb@W1+b1) ; out = z@W2+b2
__global__ __launch_bounds__(64) void k_cls(const float* __restrict__ gemb, const int* __restrict__ gcnt,
                                            const float* __restrict__ W1, const float* __restrict__ b1,
                                            const float* __restrict__ W2, const float* __restrict__ b2,
                                            float* __restrict__ out) {
    __shared__ float emb[HID];
    __shared__ float z[HID];
    int g = blockIdx.x, j = threadIdx.x;
    float cnt = fmaxf((float)gcnt[g], 1.f);
    emb[j] = gemb[g * HID + j] / cnt;
    __syncthreads();
    float acc = b1[j];
    for (int k = 0; k < HID; k++) acc += emb[k] * W1[k * HID + j];
    z[j] = fmaxf(acc, 0.f);
    __syncthreads();
    if (j < 2) {
        float o = b2[j];
        for (int k = 0; k < HID; k++) o += z[k] * W2[k * 2 + j];
        out[g * 2 + j] = o;
    }
}

extern "C" void kernel_launch(void* const* d_in, const int* in_sizes, int n_in,
                              void* d_out, int out_size, void* d_ws, size_t ws_size,
                              hipStream_t stream) {
    const float* x     = (const float*)d_in[0];
    const int*   ei    = (const int*)d_in[1];
    const int*   src   = ei;
    const int*   dst   = ei + N_EDGES;
    const int*   batch = (const int*)d_in[2];
    const float* Win   = (const float*)d_in[3];
    const float* bin_  = (const float*)d_in[4];
    const float* convW = (const float*)d_in[5];
    const float* convB = (const float*)d_in[6];
    const float* gnW   = (const float*)d_in[7];
    const float* gnB   = (const float*)d_in[8];
    const float* gnS   = (const float*)d_in[9];
    const float* W1    = (const float*)d_in[10];
    const float* b1    = (const float*)d_in[11];
    const float* W2    = (const float*)d_in[12];
    const float* b2    = (const float*)d_in[13];
    float* out = (float*)d_out;

    char* ws = (char*)d_ws;
    size_t off = 0;
    auto alloc = [&](size_t bytes) -> void* {
        void* p = ws + off;
        off = (off + bytes + 255) & ~(size_t)255;
        return p;
    };
    // ---- zeroed region (one memset) ----
    int*   degE   = (int*)alloc((size_t)N_NODES * 4);
    int*   cursor = (int*)alloc((size_t)N_NODES * 4);
    int*   gcnt   = (int*)alloc((size_t)N_GRAPHS * 4);
    float* gS1    = (float*)alloc((size_t)NLAY * N_GRAPHS * HID * 4);
    float* gS2    = (float*)alloc((size_t)NLAY * N_GRAPHS * HID * 4);
    float* gemb   = (float*)alloc((size_t)N_GRAPHS * HID * 4);
    size_t zeroBytes = off;
    // ---- rest ----
    float* dinv   = (float*)alloc((size_t)N_NODES * 4);
    int*   rowptr = (int*)alloc((size_t)(N_NODES + 1) * 4);
    int*   tmp    = (int*)alloc((size_t)N_NODES * 4);
    int*   bsum   = (int*)alloc(128 * 4);
    float* h      = (float*)alloc((size_t)N_NODES * HID * 4);
    float* y      = (float*)alloc((size_t)N_NODES * HID * 4);
    float* c      = (float*)alloc((size_t)N_NODES * HID * 4);
    int*   cols   = (int*)alloc((size_t)N_EDGES * 4);
    float* gmean  = (float*)alloc((size_t)N_GRAPHS * HID * 4);
    float* ginv   = (float*)alloc((size_t)N_GRAPHS * HID * 4);
    (void)ws_size; (void)in_sizes; (void)n_in; (void)out_size;

    hipMemsetAsync(d_ws, 0, zeroBytes, stream);

    const int EB = (N_EDGES + 255) / 256;            // 12500
    const int NB = (N_NODES + 255) / 256;            // 391
    const int NHB = (N_NODES * HID + 255) / 256;     // 25000
    const int SCB = (N_NODES + 1023) / 1024;         // 98

    k_deg<<<EB, 256, 0, stream>>>(dst, degE);
    k_dinv<<<NB, 256, 0, stream>>>(degE, batch, dinv, gcnt);
    k_scan1<<<SCB, 1024, 0, stream>>>(degE, tmp, bsum);
    k_scan2<<<1, 128, 0, stream>>>(bsum, SCB);
    k_scan3<<<NB, 256, 0, stream>>>(tmp, bsum, rowptr);
    k_fill<<<EB, 256, 0, stream>>>(src, dst, rowptr, cursor, cols);

    k_h0<<<NHB, 256, 0, stream>>>(x, Win, bin_, h);

    const int XWB = (N_NODES + 63) / 64;             // 1563
    for (int l = 0; l < NLAY; l++) {
        const float* Wl   = convW + (size_t)l * HID * HID;
        const float* bl   = convB + (size_t)l * HID;
        const float* gnWl = gnW + (size_t)l * HID;
        const float* gnBl = gnB + (size_t)l * HID;
        const float* gnSl = gnS + (size_t)l * HID;
        float* S1l = gS1 + (size_t)l * N_GRAPHS * HID;
        float* S2l = gS2 + (size_t)l * N_GRAPHS * HID;

        k_xw<<<XWB, 256, 0, stream>>>(h, Wl, dinv, y);
        k_agg<<<NHB, 256, 0, stream>>>(y, rowptr, cols, dinv, bl, batch, c, S1l, S2l);
        k_stats<<<(N_GRAPHS * HID + 255) / 256, 256, 0, stream>>>(S1l, S2l, gcnt, gnSl, gmean, ginv);
        k_update<<<NHB, 256, 0, stream>>>(c, batch, gmean, ginv, gnWl, gnBl, gnSl, h, gemb,
                                          (l == NLAY - 1) ? 1 : 0);
    }

    k_cls<<<N_GRAPHS, 64, 0, stream>>>(gemb, gcnt, W1, b1, W2, b2, out);
}

// Round 2
// 1213.913 us; speedup vs baseline: 1.1030x; 1.1030x over previous
//
#include <hip/hip_runtime.h>

#define N_NODES 100000
#define N_EDGES 3200000
#define N_GRAPHS 256
#define NODE_DIM 7
#define HID 64
#define NLAY 3
#define EPSV 1e-5f

static __device__ __forceinline__ void f4add(float4& a, const float4& b) {
    a.x += b.x; a.y += b.y; a.z += b.z; a.w += b.w;
}

// ---------------- graph-structure kernels (run once per call) ----------------

__global__ __launch_bounds__(256) void k_deg(const int* __restrict__ dst, int* __restrict__ degE) {
    int e = blockIdx.x * 256 + threadIdx.x;
    if (e < N_EDGES) atomicAdd(&degE[dst[e]], 1);
}

__global__ __launch_bounds__(256) void k_dinv(const int* __restrict__ degE, const int* __restrict__ batch,
                                              float* __restrict__ dinv, int* __restrict__ gcnt) {
    int v = blockIdx.x * 256 + threadIdx.x;
    if (v < N_NODES) {
        dinv[v] = rsqrtf((float)(degE[v] + 1));   // +1 self-loop; always > 0
        atomicAdd(&gcnt[batch[v]], 1);
    }
}

// inclusive scan of degE within 1024-blocks
__global__ __launch_bounds__(1024) void k_scan1(const int* __restrict__ degE, int* __restrict__ tmp,
                                                int* __restrict__ bsum) {
    __shared__ int sh[1024];
    int i = blockIdx.x * 1024 + threadIdx.x;
    int v = (i < N_NODES) ? degE[i] : 0;
    sh[threadIdx.x] = v;
    __syncthreads();
    for (int ofs = 1; ofs < 1024; ofs <<= 1) {
        int t = (threadIdx.x >= (unsigned)ofs) ? sh[threadIdx.x - ofs] : 0;
        __syncthreads();
        sh[threadIdx.x] += t;
        __syncthreads();
    }
    if (i < N_NODES) tmp[i] = sh[threadIdx.x];
    if (threadIdx.x == 1023) bsum[blockIdx.x] = sh[1023];
}

__global__ __launch_bounds__(128) void k_scan2(int* __restrict__ bsum, int nb) {
    __shared__ int sh[128];
    int t = threadIdx.x;
    int v = (t < nb) ? bsum[t] : 0;
    sh[t] = v;
    __syncthreads();
    for (int ofs = 1; ofs < 128; ofs <<= 1) {
        int u = (t >= ofs) ? sh[t - ofs] : 0;
        __syncthreads();
        sh[t] += u;
        __syncthreads();
    }
    if (t < nb) bsum[t] = sh[t] - v;   // exclusive block offsets
}

// rowptr[i+1] = scan(deg); also seed cursor[i] = rowptr[i]
__global__ __launch_bounds__(256) void k_scan3(const int* __restrict__ tmp, const int* __restrict__ bsum,
                                               int* __restrict__ rowptr, int* __restrict__ cursor) {
    int i = blockIdx.x * 256 + threadIdx.x;
    if (i < N_NODES) {
        int incl = tmp[i] + bsum[i >> 10];
        rowptr[i + 1] = incl;
        int self = tmp[i] - ((i & 1023) ? 0 : 0); // dummy keep
        (void)self;
    }
    if (i == 0) rowptr[0] = 0;
    // cursor seeded in a second pass (k_seed) since rowptr[i] = incl of i-1
}

__global__ __launch_bounds__(256) void k_seed(const int* __restrict__ rowptr, int* __restrict__ cursor) {
    int i = blockIdx.x * 256 + threadIdx.x;
    if (i < N_NODES) cursor[i] = rowptr[i];
}

__global__ __launch_bounds__(256) void k_fill(const int* __restrict__ src, const int* __restrict__ dst,
                                              int* __restrict__ cursor, int* __restrict__ cols) {
    int e = blockIdx.x * 256 + threadIdx.x;
    if (e < N_EDGES) {
        int pos = atomicAdd(&cursor[dst[e]], 1);
        cols[pos] = src[e];
    }
}

// ---------------- per-layer kernels ----------------

// h0 = x @ Win + bin
__global__ __launch_bounds__(256) void k_h0(const float* __restrict__ x, const float* __restrict__ Win,
                                            const float* __restrict__ b, float* __restrict__ h) {
    int i = blockIdx.x * 256 + threadIdx.x;
    if (i >= N_NODES * HID) return;
    int v = i >> 6, j = i & 63;
    float acc = b[j];
#pragma unroll
    for (int k = 0; k < NODE_DIM; k++) acc += x[v * NODE_DIM + k] * Win[k * HID + j];
    h[i] = acc;
}

// y = (h @ W) * dinv[:,None] ; 64 nodes per block, LDS-staged tiles
__global__ __launch_bounds__(256) void k_xw(const float* __restrict__ h, const float* __restrict__ W,
                                            const float* __restrict__ dinv, float* __restrict__ y) {
    __shared__ float Ws[HID][HID];
    __shared__ float Hs[64][HID];
    int t = threadIdx.x;
    int nb = blockIdx.x * 64;
#pragma unroll
    for (int k = 0; k < 16; k++) {
        int idx = t + k * 256;
        Ws[idx >> 6][idx & 63] = W[idx];
        int r = idx >> 6, cc = idx & 63;
        int node = nb + r;
        Hs[r][cc] = (node < N_NODES) ? h[(size_t)node * HID + cc] : 0.f;
    }
    __syncthreads();
    int j = t & 63;
    int r0 = t >> 6;          // wave-uniform (0..3)
    for (int rr = r0; rr < 64; rr += 4) {
        int node = nb + rr;
        if (node >= N_NODES) continue;
        float acc = 0.f;
#pragma unroll
        for (int k = 0; k < HID; k++) acc += Hs[rr][k] * Ws[k][j];
        y[(size_t)node * HID + j] = acc * dinv[node];
    }
}

// c[v] = dinv[v]*(y[v] + sum_{in-edges} y[s]) + bias ; fused per-graph S1/S2 stats.
// One wave per node; lane-group q (16 lanes) gathers edge e+q as float4 -> 1KB/instr.
__global__ __launch_bounds__(256) void k_agg(const float* __restrict__ y, const int* __restrict__ rowptr,
                                             const int* __restrict__ cols, const float* __restrict__ dinv,
                                             const float* __restrict__ bias, const int* __restrict__ batch,
                                             float* __restrict__ c, float* __restrict__ gS1,
                                             float* __restrict__ gS2) {
    __shared__ float sh1[4][HID];
    __shared__ float sh2[4][HID];
    __shared__ int shg[4];
    const int t = threadIdx.x;
    const int w = t >> 6;          // wave in block
    const int lane = t & 63;
    const int v = blockIdx.x * 4 + w;    // grid covers N_NODES exactly
    const int q = lane >> 4;       // edge group 0..3
    const int f4 = lane & 15;      // float4 slot within row
    const float4* __restrict__ y4 = (const float4*)y;

    float4 acc = make_float4(0.f, 0.f, 0.f, 0.f);
    float4 acc2 = make_float4(0.f, 0.f, 0.f, 0.f);
    if (q == 0) acc = y4[(size_t)v * 16 + f4];          // self-loop
    int e0 = rowptr[v], e1 = rowptr[v + 1];
    int e = e0;
    for (; e + 7 < e1; e += 8) {
        int s0 = cols[e + q];
        int s1 = cols[e + 4 + q];
        float4 t0 = y4[(size_t)s0 * 16 + f4];
        float4 t1 = y4[(size_t)s1 * 16 + f4];
        f4add(acc, t0);
        f4add(acc2, t1);
    }
    if (e + 3 < e1) {
        int s0 = cols[e + q];
        f4add(acc, y4[(size_t)s0 * 16 + f4]);
        e += 4;
    }
    if (e + q < e1) {
        int s0 = cols[e + q];
        f4add(acc2, y4[(size_t)s0 * 16 + f4]);
    }
    f4add(acc, acc2);
    // reduce across the 4 lane-groups (masks 16, 32)
    acc.x += __shfl_xor(acc.x, 16); acc.y += __shfl_xor(acc.y, 16);
    acc.z += __shfl_xor(acc.z, 16); acc.w += __shfl_xor(acc.w, 16);
    acc.x += __shfl_xor(acc.x, 32); acc.y += __shfl_xor(acc.y, 32);
    acc.z += __shfl_xor(acc.z, 32); acc.w += __shfl_xor(acc.w, 32);

    float dv = dinv[v];
    float4 bb = ((const float4*)bias)[f4];
    float4 cv;
    cv.x = dv * acc.x + bb.x;
    cv.y = dv * acc.y + bb.y;
    cv.z = dv * acc.z + bb.z;
    cv.w = dv * acc.w + bb.w;
    if (q == 0) {
        ((float4*)c)[(size_t)v * 16 + f4] = cv;
        sh1[w][f4 * 4 + 0] = cv.x; sh2[w][f4 * 4 + 0] = cv.x * cv.x;
        sh1[w][f4 * 4 + 1] = cv.y; sh2[w][f4 * 4 + 1] = cv.y * cv.y;
        sh1[w][f4 * 4 + 2] = cv.z; sh2[w][f4 * 4 + 2] = cv.z * cv.z;
        sh1[w][f4 * 4 + 3] = cv.w; sh2[w][f4 * 4 + 3] = cv.w * cv.w;
        if (f4 == 0) shg[w] = batch[v];
    }
    __syncthreads();
    if (w == 0) {   // one wave reduces block stats: 2 (or 8) atomics/feature per 4 nodes
        int g0 = shg[0];
        bool uni = (shg[1] == g0) && (shg[2] == g0) && (shg[3] == g0);
        if (uni) {
            float s1 = sh1[0][lane] + sh1[1][lane] + sh1[2][lane] + sh1[3][lane];
            float s2 = sh2[0][lane] + sh2[1][lane] + sh2[2][lane] + sh2[3][lane];
            atomicAdd(&gS1[g0 * HID + lane], s1);
            atomicAdd(&gS2[g0 * HID + lane], s2);
        } else {
#pragma unroll
            for (int ww = 0; ww < 4; ww++) {
                atomicAdd(&gS1[shg[ww] * HID + lane], sh1[ww][lane]);
                atomicAdd(&gS2[shg[ww] * HID + lane], sh2[ww][lane]);
            }
        }
    }
}

// per-graph mean / inv-std.  var = S2/cnt - 2*s*m^2 + s^2*m^2
__global__ __launch_bounds__(256) void k_stats(const float* __restrict__ gS1, const float* __restrict__ gS2,
                                               const int* __restrict__ gcnt, const float* __restrict__ gnS_l,
                                               float* __restrict__ gmean, float* __restrict__ ginv) {
    int i = blockIdx.x * 256 + threadIdx.x;
    if (i >= N_GRAPHS * HID) return;
    int g = i >> 6, j = i & 63;
    float cnt = fmaxf((float)gcnt[g], 1.f);
    float m = gS1[i] / cnt;
    float s = gnS_l[j];
    float var = gS2[i] / cnt - 2.f * s * m * m + s * s * m * m;
    gmean[i] = m;
    ginv[i] = rsqrtf(var + EPSV);
}

// h += relu(gnW*(c - s*mean)*invstd + gnB) ; optionally accumulate graph-emb sums
__global__ __launch_bounds__(256) void k_update(const float* __restrict__ c, const int* __restrict__ batch,
                                                const float* __restrict__ gmean, const float* __restrict__ ginv,
                                                const float* __restrict__ gnW_l, const float* __restrict__ gnB_l,
                                                const float* __restrict__ gnS_l, float* __restrict__ h,
                                                float* __restrict__ gemb, int accum_emb) {
    __shared__ float shh[4][HID];
    __shared__ int shg[4];
    int t = threadIdx.x;
    int i = blockIdx.x * 256 + t;          // grid covers N_NODES*HID exactly
    int v = i >> 6, j = i & 63, w = t >> 6;
    int g = batch[v];
    float outv = c[i] - gnS_l[j] * gmean[g * HID + j];
    float val = gnW_l[j] * outv * ginv[g * HID + j] + gnB_l[j];
    float hn = h[i] + fmaxf(val, 0.f);
    h[i] = hn;
    if (accum_emb) {
        shh[w][j] = hn;
        if (j == 0) shg[w] = g;
        __syncthreads();
        if (w == 0) {
            int g0 = shg[0];
            bool uni = (shg[1] == g0) && (shg[2] == g0) && (shg[3] == g0);
            if (uni) {
                atomicAdd(&gemb[g0 * HID + j], shh[0][j] + shh[1][j] + shh[2][j] + shh[3][j]);
            } else {
#pragma unroll
                for (int ww = 0; ww < 4; ww++)
                    atomicAdd(&gemb[shg[ww] * HID + j], shh[ww][j]);
            }
        }
    }
}

// classifier head: emb = gemb/cnt ; z = relu(emb@W1+b1) ; out = z@W2+b2
__global__ __launch_bounds__(64) void k_cls(const float* __restrict__ gemb, const int* __restrict__ gcnt,
                                            const float* __restrict__ W1, const float* __restrict__ b1,
                                            const float* __restrict__ W2, const float* __restrict__ b2,
                                            float* __restrict__ out) {
    __shared__ float emb[HID];
    __shared__ float z[HID];
    int g = blockIdx.x, j = threadIdx.x;
    float cnt = fmaxf((float)gcnt[g], 1.f);
    emb[j] = gemb[g * HID + j] / cnt;
    __syncthreads();
    float acc = b1[j];
    for (int k = 0; k < HID; k++) acc += emb[k] * W1[k * HID + j];
    z[j] = fmaxf(acc, 0.f);
    __syncthreads();
    if (j < 2) {
        float o = b2[j];
        for (int k = 0; k < HID; k++) o += z[k] * W2[k * 2 + j];
        out[g * 2 + j] = o;
    }
}

extern "C" void kernel_launch(void* const* d_in, const int* in_sizes, int n_in,
                              void* d_out, int out_size, void* d_ws, size_t ws_size,
                              hipStream_t stream) {
    const float* x     = (const float*)d_in[0];
    const int*   ei    = (const int*)d_in[1];
    const int*   src   = ei;
    const int*   dst   = ei + N_EDGES;
    const int*   batch = (const int*)d_in[2];
    const float* Win   = (const float*)d_in[3];
    const float* bin_  = (const float*)d_in[4];
    const float* convW = (const float*)d_in[5];
    const float* convB = (const float*)d_in[6];
    const float* gnW   = (const float*)d_in[7];
    const float* gnB   = (const float*)d_in[8];
    const float* gnS   = (const float*)d_in[9];
    const float* W1    = (const float*)d_in[10];
    const float* b1    = (const float*)d_in[11];
    const float* W2    = (const float*)d_in[12];
    const float* b2    = (const float*)d_in[13];
    float* out = (float*)d_out;

    char* ws = (char*)d_ws;
    size_t off = 0;
    auto alloc = [&](size_t bytes) -> void* {
        void* p = ws + off;
        off = (off + bytes + 255) & ~(size_t)255;
        return p;
    };
    // ---- zeroed region (one memset) ----
    int*   degE   = (int*)alloc((size_t)N_NODES * 4);
    int*   gcnt   = (int*)alloc((size_t)N_GRAPHS * 4);
    float* gS1    = (float*)alloc((size_t)NLAY * N_GRAPHS * HID * 4);
    float* gS2    = (float*)alloc((size_t)NLAY * N_GRAPHS * HID * 4);
    float* gemb   = (float*)alloc((size_t)N_GRAPHS * HID * 4);
    size_t zeroBytes = off;
    // ---- rest ----
    int*   cursor = (int*)alloc((size_t)N_NODES * 4);
    float* dinv   = (float*)alloc((size_t)N_NODES * 4);
    int*   rowptr = (int*)alloc((size_t)(N_NODES + 1) * 4);
    int*   tmp    = (int*)alloc((size_t)N_NODES * 4);
    int*   bsum   = (int*)alloc(128 * 4);
    float* h      = (float*)alloc((size_t)N_NODES * HID * 4);
    float* y      = (float*)alloc((size_t)N_NODES * HID * 4);
    float* c      = (float*)alloc((size_t)N_NODES * HID * 4);
    int*   cols   = (int*)alloc((size_t)N_EDGES * 4);
    float* gmean  = (float*)alloc((size_t)N_GRAPHS * HID * 4);
    float* ginv   = (float*)alloc((size_t)N_GRAPHS * HID * 4);
    (void)ws_size; (void)in_sizes; (void)n_in; (void)out_size;

    hipMemsetAsync(d_ws, 0, zeroBytes, stream);

    const int EB = (N_EDGES + 255) / 256;            // 12500
    const int NB = (N_NODES + 255) / 256;            // 391
    const int NHB = (N_NODES * HID + 255) / 256;     // 25000
    const int SCB = (N_NODES + 1023) / 1024;         // 98

    k_deg<<<EB, 256, 0, stream>>>(dst, degE);
    k_dinv<<<NB, 256, 0, stream>>>(degE, batch, dinv, gcnt);
    k_scan1<<<SCB, 1024, 0, stream>>>(degE, tmp, bsum);
    k_scan2<<<1, 128, 0, stream>>>(bsum, SCB);
    k_scan3<<<NB, 256, 0, stream>>>(tmp, bsum, rowptr, cursor);
    k_seed<<<NB, 256, 0, stream>>>(rowptr, cursor);
    k_fill<<<EB, 256, 0, stream>>>(src, dst, cursor, cols);

    k_h0<<<NHB, 256, 0, stream>>>(x, Win, bin_, h);

    const int XWB = (N_NODES + 63) / 64;             // 1563
    for (int l = 0; l < NLAY; l++) {
        const float* Wl   = convW + (size_t)l * HID * HID;
        const float* bl   = convB + (size_t)l * HID;
        const float* gnWl = gnW + (size_t)l * HID;
        const float* gnBl = gnB + (size_t)l * HID;
        const float* gnSl = gnS + (size_t)l * HID;
        float* S1l = gS1 + (size_t)l * N_GRAPHS * HID;
        float* S2l = gS2 + (size_t)l * N_GRAPHS * HID;

        k_xw<<<XWB, 256, 0, stream>>>(h, Wl, dinv, y);
        k_agg<<<N_NODES / 4, 256, 0, stream>>>(y, rowptr, cols, dinv, bl, batch, c, S1l, S2l);
        k_stats<<<(N_GRAPHS * HID + 255) / 256, 256, 0, stream>>>(S1l, S2l, gcnt, gnSl, gmean, ginv);
        k_update<<<NHB, 256, 0, stream>>>(c, batch, gmean, ginv, gnWl, gnBl, gnSl, h, gemb,
                                          (l == NLAY - 1) ? 1 : 0);
    }

    k_cls<<<N_GRAPHS, 64, 0, stream>>>(gemb, gcnt, W1, b1, W2, b2, out);
}

// Round 3
// 1190.554 us; speedup vs baseline: 1.1246x; 1.0196x over previous
//
#include <hip/hip_runtime.h>

#define N_NODES 100000
#define N_EDGES 3200000
#define N_GRAPHS 256
#define NODE_DIM 7
#define HID 64
#define NLAY 3
#define EPSV 1e-5f
#define SWEEPS 8
#define SWEEP_W (N_NODES / SWEEPS)   // 12500

static __device__ __forceinline__ void f4add(float4& a, const float4& b) {
    a.x += b.x; a.y += b.y; a.z += b.z; a.w += b.w;
}

// ---------------- graph-structure kernels (run once per call) ----------------

__global__ __launch_bounds__(256) void k_deg(const int* __restrict__ dst, int* __restrict__ degE) {
    int e4 = blockIdx.x * 256 + threadIdx.x;       // N_EDGES/4 threads
    int4 d = ((const int4*)dst)[e4];
    atomicAdd(&degE[d.x], 1);
    atomicAdd(&degE[d.y], 1);
    atomicAdd(&degE[d.z], 1);
    atomicAdd(&degE[d.w], 1);
}

__global__ __launch_bounds__(256) void k_dinv(const int* __restrict__ degE, const int* __restrict__ batch,
                                              float* __restrict__ dinv, int* __restrict__ gcnt) {
    int v = blockIdx.x * 256 + threadIdx.x;
    if (v < N_NODES) {
        dinv[v] = rsqrtf((float)(degE[v] + 1));   // +1 self-loop; always > 0
        atomicAdd(&gcnt[batch[v]], 1);
    }
}

// inclusive scan of degE within 1024-blocks
__global__ __launch_bounds__(1024) void k_scan1(const int* __restrict__ degE, int* __restrict__ tmp,
                                                int* __restrict__ bsum) {
    __shared__ int sh[1024];
    int i = blockIdx.x * 1024 + threadIdx.x;
    int v = (i < N_NODES) ? degE[i] : 0;
    sh[threadIdx.x] = v;
    __syncthreads();
    for (int ofs = 1; ofs < 1024; ofs <<= 1) {
        int t = (threadIdx.x >= (unsigned)ofs) ? sh[threadIdx.x - ofs] : 0;
        __syncthreads();
        sh[threadIdx.x] += t;
        __syncthreads();
    }
    if (i < N_NODES) tmp[i] = sh[threadIdx.x];
    if (threadIdx.x == 1023) bsum[blockIdx.x] = sh[1023];
}

__global__ __launch_bounds__(128) void k_scan2(int* __restrict__ bsum, int nb) {
    __shared__ int sh[128];
    int t = threadIdx.x;
    int v = (t < nb) ? bsum[t] : 0;
    sh[t] = v;
    __syncthreads();
    for (int ofs = 1; ofs < 128; ofs <<= 1) {
        int u = (t >= ofs) ? sh[t - ofs] : 0;
        __syncthreads();
        sh[t] += u;
        __syncthreads();
    }
    if (t < nb) bsum[t] = sh[t] - v;   // exclusive block offsets
}

// rowptr[i+1] = inclusive scan; also seed cursor
__global__ __launch_bounds__(256) void k_scan3(const int* __restrict__ tmp, const int* __restrict__ bsum,
                                               int* __restrict__ rowptr, int* __restrict__ cursor) {
    int i = blockIdx.x * 256 + threadIdx.x;
    if (i < N_NODES) {
        int incl = tmp[i] + bsum[i >> 10];
        rowptr[i + 1] = incl;
        if (i + 1 < N_NODES) cursor[i + 1] = incl;
    }
    if (i == 0) { rowptr[0] = 0; cursor[0] = 0; }
}

// range-swept fill: only edges with dst in [lo, lo+SWEEP_W) are scattered,
// confining atomic window (~50KB) and write window (~1.6MB) to L2.
__global__ __launch_bounds__(256) void k_fill(const int* __restrict__ src, const int* __restrict__ dst,
                                              int* __restrict__ cursor, int* __restrict__ cols, int lo) {
    int e4 = blockIdx.x * 256 + threadIdx.x;       // N_EDGES/4 threads
    int4 d = ((const int4*)dst)[e4];
    int4 s = ((const int4*)src)[e4];
    int hi = lo + SWEEP_W;
    if (d.x >= lo && d.x < hi) cols[atomicAdd(&cursor[d.x], 1)] = s.x;
    if (d.y >= lo && d.y < hi) cols[atomicAdd(&cursor[d.y], 1)] = s.y;
    if (d.z >= lo && d.z < hi) cols[atomicAdd(&cursor[d.z], 1)] = s.z;
    if (d.w >= lo && d.w < hi) cols[atomicAdd(&cursor[d.w], 1)] = s.w;
}

// ---------------- per-layer kernels ----------------

// h0 = x @ Win + bin
__global__ __launch_bounds__(256) void k_h0(const float* __restrict__ x, const float* __restrict__ Win,
                                            const float* __restrict__ b, float* __restrict__ h) {
    int i = blockIdx.x * 256 + threadIdx.x;
    if (i >= N_NODES * HID) return;
    int v = i >> 6, j = i & 63;
    float acc = b[j];
#pragma unroll
    for (int k = 0; k < NODE_DIM; k++) acc += x[v * NODE_DIM + k] * Win[k * HID + j];
    h[i] = acc;
}

// y = (h @ W) * dinv[:,None] ; 64 nodes per block; 4-row register blocking,
// float4 broadcast reads of Hs rows (8 LDS reads per 16 FMA).
__global__ __launch_bounds__(256) void k_xw(const float* __restrict__ h, const float* __restrict__ W,
                                            const float* __restrict__ dinv, float* __restrict__ y) {
    __shared__ float Ws[HID][HID];
    __shared__ float Hs[64][HID];
    int t = threadIdx.x;
    int nb = blockIdx.x * 64;
#pragma unroll
    for (int it = 0; it < 4; it++) {
        int i = t + it * 256;                 // float4 index, 1024 total
        ((float4*)Ws)[i] = ((const float4*)W)[i];
        int r = i >> 4, c4 = i & 15;
        int node = nb + r;
        float4 hv = make_float4(0.f, 0.f, 0.f, 0.f);
        if (node < N_NODES) hv = ((const float4*)h)[(size_t)node * 16 + c4];
        ((float4*)&Hs[r][0])[c4] = hv;
    }
    __syncthreads();
    int j = t & 63;
    int r0 = t >> 6;          // 0..3
#pragma unroll
    for (int o = 0; o < 4; o++) {
        int ra = r0 + o * 16;                 // rows ra, ra+4, ra+8, ra+12
        float a0 = 0.f, a1 = 0.f, a2 = 0.f, a3 = 0.f;
#pragma unroll
        for (int k4 = 0; k4 < 16; k4++) {
            float4 h0 = ((const float4*)&Hs[ra][0])[k4];
            float4 h1 = ((const float4*)&Hs[ra + 4][0])[k4];
            float4 h2 = ((const float4*)&Hs[ra + 8][0])[k4];
            float4 h3 = ((const float4*)&Hs[ra + 12][0])[k4];
            float w0 = Ws[k4 * 4 + 0][j];
            float w1 = Ws[k4 * 4 + 1][j];
            float w2 = Ws[k4 * 4 + 2][j];
            float w3 = Ws[k4 * 4 + 3][j];
            a0 += h0.x * w0 + h0.y * w1 + h0.z * w2 + h0.w * w3;
            a1 += h1.x * w0 + h1.y * w1 + h1.z * w2 + h1.w * w3;
            a2 += h2.x * w0 + h2.y * w1 + h2.z * w2 + h2.w * w3;
            a3 += h3.x * w0 + h3.y * w1 + h3.z * w2 + h3.w * w3;
        }
        int n0 = nb + ra, n1 = n0 + 4, n2 = n0 + 8, n3 = n0 + 12;
        if (n0 < N_NODES) y[(size_t)n0 * HID + j] = a0 * dinv[n0];
        if (n1 < N_NODES) y[(size_t)n1 * HID + j] = a1 * dinv[n1];
        if (n2 < N_NODES) y[(size_t)n2 * HID + j] = a2 * dinv[n2];
        if (n3 < N_NODES) y[(size_t)n3 * HID + j] = a3 * dinv[n3];
    }
}

// c[v] = dinv[v]*(y[v] + sum_{in-edges} y[s]) + bias ; fused per-graph S1/S2 stats.
// One wave per node; lane-group q (16 lanes) gathers edge e+q as float4; 16-edge unroll.
__global__ __launch_bounds__(256) void k_agg(const float* __restrict__ y, const int* __restrict__ rowptr,
                                             const int* __restrict__ cols, const float* __restrict__ dinv,
                                             const float* __restrict__ bias, const int* __restrict__ batch,
                                             float* __restrict__ c, float* __restrict__ gS1,
                                             float* __restrict__ gS2) {
    __shared__ float sh1[4][HID];
    __shared__ float sh2[4][HID];
    __shared__ int shg[4];
    const int t = threadIdx.x;
    const int w = t >> 6;          // wave in block
    const int lane = t & 63;
    const int v = blockIdx.x * 4 + w;    // grid covers N_NODES exactly
    const int q = lane >> 4;       // edge group 0..3
    const int f4 = lane & 15;      // float4 slot within row
    const float4* __restrict__ y4 = (const float4*)y;

    float4 acc0 = make_float4(0.f, 0.f, 0.f, 0.f);
    float4 acc1 = acc0, acc2 = acc0, acc3 = acc0;
    if (q == 0) acc0 = y4[(size_t)v * 16 + f4];          // self-loop
    int e0 = rowptr[v], e1 = rowptr[v + 1];
    int e = e0;
    for (; e + 15 < e1; e += 16) {
        int s0 = cols[e + q];
        int s1 = cols[e + 4 + q];
        int s2 = cols[e + 8 + q];
        int s3 = cols[e + 12 + q];
        f4add(acc0, y4[(size_t)s0 * 16 + f4]);
        f4add(acc1, y4[(size_t)s1 * 16 + f4]);
        f4add(acc2, y4[(size_t)s2 * 16 + f4]);
        f4add(acc3, y4[(size_t)s3 * 16 + f4]);
    }
    if (e + 7 < e1) {
        int s0 = cols[e + q];
        int s1 = cols[e + 4 + q];
        f4add(acc0, y4[(size_t)s0 * 16 + f4]);
        f4add(acc1, y4[(size_t)s1 * 16 + f4]);
        e += 8;
    }
    if (e + 3 < e1) {
        int s0 = cols[e + q];
        f4add(acc2, y4[(size_t)s0 * 16 + f4]);
        e += 4;
    }
    if (e + q < e1) {
        int s0 = cols[e + q];
        f4add(acc3, y4[(size_t)s0 * 16 + f4]);
    }
    f4add(acc0, acc1);
    f4add(acc2, acc3);
    f4add(acc0, acc2);
    // reduce across the 4 lane-groups (masks 16, 32)
    acc0.x += __shfl_xor(acc0.x, 16); acc0.y += __shfl_xor(acc0.y, 16);
    acc0.z += __shfl_xor(acc0.z, 16); acc0.w += __shfl_xor(acc0.w, 16);
    acc0.x += __shfl_xor(acc0.x, 32); acc0.y += __shfl_xor(acc0.y, 32);
    acc0.z += __shfl_xor(acc0.z, 32); acc0.w += __shfl_xor(acc0.w, 32);

    float dv = dinv[v];
    float4 bb = ((const float4*)bias)[f4];
    float4 cv;
    cv.x = dv * acc0.x + bb.x;
    cv.y = dv * acc0.y + bb.y;
    cv.z = dv * acc0.z + bb.z;
    cv.w = dv * acc0.w + bb.w;
    if (q == 0) {
        ((float4*)c)[(size_t)v * 16 + f4] = cv;
        sh1[w][f4 * 4 + 0] = cv.x; sh2[w][f4 * 4 + 0] = cv.x * cv.x;
        sh1[w][f4 * 4 + 1] = cv.y; sh2[w][f4 * 4 + 1] = cv.y * cv.y;
        sh1[w][f4 * 4 + 2] = cv.z; sh2[w][f4 * 4 + 2] = cv.z * cv.z;
        sh1[w][f4 * 4 + 3] = cv.w; sh2[w][f4 * 4 + 3] = cv.w * cv.w;
        if (f4 == 0) shg[w] = batch[v];
    }
    __syncthreads();
    if (w == 0) {   // one wave reduces block stats
        int g0 = shg[0];
        bool uni = (shg[1] == g0) && (shg[2] == g0) && (shg[3] == g0);
        if (uni) {
            float s1 = sh1[0][lane] + sh1[1][lane] + sh1[2][lane] + sh1[3][lane];
            float s2 = sh2[0][lane] + sh2[1][lane] + sh2[2][lane] + sh2[3][lane];
            atomicAdd(&gS1[g0 * HID + lane], s1);
            atomicAdd(&gS2[g0 * HID + lane], s2);
        } else {
#pragma unroll
            for (int ww = 0; ww < 4; ww++) {
                atomicAdd(&gS1[shg[ww] * HID + lane], sh1[ww][lane]);
                atomicAdd(&gS2[shg[ww] * HID + lane], sh2[ww][lane]);
            }
        }
    }
}

// per-graph mean / inv-std.  var = S2/cnt - 2*s*m^2 + s^2*m^2
__global__ __launch_bounds__(256) void k_stats(const float* __restrict__ gS1, const float* __restrict__ gS2,
                                               const int* __restrict__ gcnt, const float* __restrict__ gnS_l,
                                               float* __restrict__ gmean, float* __restrict__ ginv) {
    int i = blockIdx.x * 256 + threadIdx.x;
    if (i >= N_GRAPHS * HID) return;
    int g = i >> 6, j = i & 63;
    float cnt = fmaxf((float)gcnt[g], 1.f);
    float m = gS1[i] / cnt;
    float s = gnS_l[j];
    float var = gS2[i] / cnt - 2.f * s * m * m + s * s * m * m;
    gmean[i] = m;
    ginv[i] = rsqrtf(var + EPSV);
}

// h += relu(gnW*(c - s*mean)*invstd + gnB), float4 lanes; 16 nodes/block;
// optional block-reduced graph-emb accumulation.
__global__ __launch_bounds__(256) void k_update(const float* __restrict__ c, const int* __restrict__ batch,
                                                const float* __restrict__ gmean, const float* __restrict__ ginv,
                                                const float* __restrict__ gnW_l, const float* __restrict__ gnB_l,
                                                const float* __restrict__ gnS_l, float* __restrict__ h,
                                                float* __restrict__ gemb, int accum_emb) {
    __shared__ float4 shh[16][16];
    __shared__ int shg[16];
    __shared__ int uniS;
    int t = threadIdx.x;
    int i = blockIdx.x * 256 + t;          // float4 index; grid covers N_NODES*16 exactly
    int v = i >> 4, f = i & 15, r = t >> 4;
    int g = batch[v];
    float4 c4 = ((const float4*)c)[i];
    float4 m4 = ((const float4*)gmean)[g * 16 + f];
    float4 i4 = ((const float4*)ginv)[g * 16 + f];
    float4 w4 = ((const float4*)gnW_l)[f];
    float4 b4 = ((const float4*)gnB_l)[f];
    float4 s4 = ((const float4*)gnS_l)[f];
    float4 h4 = ((const float4*)h)[i];
    float4 hn;
    hn.x = h4.x + fmaxf(w4.x * (c4.x - s4.x * m4.x) * i4.x + b4.x, 0.f);
    hn.y = h4.y + fmaxf(w4.y * (c4.y - s4.y * m4.y) * i4.y + b4.y, 0.f);
    hn.z = h4.z + fmaxf(w4.z * (c4.z - s4.z * m4.z) * i4.z + b4.z, 0.f);
    hn.w = h4.w + fmaxf(w4.w * (c4.w - s4.w * m4.w) * i4.w + b4.w, 0.f);
    ((float4*)h)[i] = hn;
    if (accum_emb) {
        shh[r][f] = hn;
        if (f == 0) shg[r] = g;
        if (t == 0) uniS = 1;
        __syncthreads();
        if (t < 15 && shg[t + 1] != shg[0]) uniS = 0;
        __syncthreads();
        if (uniS) {
            if (t < 128) f4add(shh[t >> 4][t & 15], shh[(t >> 4) + 8][t & 15]);
            __syncthreads();
            if (t < 64) f4add(shh[t >> 4][t & 15], shh[(t >> 4) + 4][t & 15]);
            __syncthreads();
            if (t < 32) f4add(shh[t >> 4][t & 15], shh[(t >> 4) + 2][t & 15]);
            __syncthreads();
            if (t < 16) {
                f4add(shh[0][t], shh[1][t]);
                float4 s = shh[0][t];
                int g0 = shg[0];
                atomicAdd(&gemb[g0 * HID + t * 4 + 0], s.x);
                atomicAdd(&gemb[g0 * HID + t * 4 + 1], s.y);
                atomicAdd(&gemb[g0 * HID + t * 4 + 2], s.z);
                atomicAdd(&gemb[g0 * HID + t * 4 + 3], s.w);
            }
        } else if (t < 16) {
#pragma unroll
            for (int rr = 0; rr < 16; rr++) {
                float4 s = shh[rr][t];
                int gg = shg[rr];
                atomicAdd(&gemb[gg * HID + t * 4 + 0], s.x);
                atomicAdd(&gemb[gg * HID + t * 4 + 1], s.y);
                atomicAdd(&gemb[gg * HID + t * 4 + 2], s.z);
                atomicAdd(&gemb[gg * HID + t * 4 + 3], s.w);
            }
        }
    }
}

// classifier head: emb = gemb/cnt ; z = relu(emb@W1+b1) ; out = z@W2+b2
__global__ __launch_bounds__(64) void k_cls(const float* __restrict__ gemb, const int* __restrict__ gcnt,
                                            const float* __restrict__ W1, const float* __restrict__ b1,
                                            const float* __restrict__ W2, const float* __restrict__ b2,
                                            float* __restrict__ out) {
    __shared__ float emb[HID];
    __shared__ float z[HID];
    int g = blockIdx.x, j = threadIdx.x;
    float cnt = fmaxf((float)gcnt[g], 1.f);
    emb[j] = gemb[g * HID + j] / cnt;
    __syncthreads();
    float acc = b1[j];
    for (int k = 0; k < HID; k++) acc += emb[k] * W1[k * HID + j];
    z[j] = fmaxf(acc, 0.f);
    __syncthreads();
    if (j < 2) {
        float o = b2[j];
        for (int k = 0; k < HID; k++) o += z[k] * W2[k * 2 + j];
        out[g * 2 + j] = o;
    }
}

extern "C" void kernel_launch(void* const* d_in, const int* in_sizes, int n_in,
                              void* d_out, int out_size, void* d_ws, size_t ws_size,
                              hipStream_t stream) {
    const float* x     = (const float*)d_in[0];
    const int*   ei    = (const int*)d_in[1];
    const int*   src   = ei;
    const int*   dst   = ei + N_EDGES;
    const int*   batch = (const int*)d_in[2];
    const float* Win   = (const float*)d_in[3];
    const float* bin_  = (const float*)d_in[4];
    const float* convW = (const float*)d_in[5];
    const float* convB = (const float*)d_in[6];
    const float* gnW   = (const float*)d_in[7];
    const float* gnB   = (const float*)d_in[8];
    const float* gnS   = (const float*)d_in[9];
    const float* W1    = (const float*)d_in[10];
    const float* b1    = (const float*)d_in[11];
    const float* W2    = (const float*)d_in[12];
    const float* b2    = (const float*)d_in[13];
    float* out = (float*)d_out;

    char* ws = (char*)d_ws;
    size_t off = 0;
    auto alloc = [&](size_t bytes) -> void* {
        void* p = ws + off;
        off = (off + bytes + 255) & ~(size_t)255;
        return p;
    };
    // ---- zeroed region (one memset) ----
    int*   degE   = (int*)alloc((size_t)N_NODES * 4);
    int*   gcnt   = (int*)alloc((size_t)N_GRAPHS * 4);
    float* gS1    = (float*)alloc((size_t)NLAY * N_GRAPHS * HID * 4);
    float* gS2    = (float*)alloc((size_t)NLAY * N_GRAPHS * HID * 4);
    float* gemb   = (float*)alloc((size_t)N_GRAPHS * HID * 4);
    size_t zeroBytes = off;
    // ---- rest ----
    int*   cursor = (int*)alloc((size_t)N_NODES * 4);
    float* dinv   = (float*)alloc((size_t)N_NODES * 4);
    int*   rowptr = (int*)alloc((size_t)(N_NODES + 1) * 4);
    int*   tmp    = (int*)alloc((size_t)N_NODES * 4);
    int*   bsum   = (int*)alloc(128 * 4);
    float* h      = (float*)alloc((size_t)N_NODES * HID * 4);
    float* y      = (float*)alloc((size_t)N_NODES * HID * 4);
    float* c      = (float*)alloc((size_t)N_NODES * HID * 4);
    int*   cols   = (int*)alloc((size_t)N_EDGES * 4);
    float* gmean  = (float*)alloc((size_t)N_GRAPHS * HID * 4);
    float* ginv   = (float*)alloc((size_t)N_GRAPHS * HID * 4);
    (void)ws_size; (void)in_sizes; (void)n_in; (void)out_size;

    hipMemsetAsync(d_ws, 0, zeroBytes, stream);

    const int EB4 = N_EDGES / 4 / 256;               // 3125
    const int NB = (N_NODES + 255) / 256;            // 391
    const int NHB = (N_NODES * HID + 255) / 256;     // 25000
    const int SCB = (N_NODES + 1023) / 1024;         // 98

    k_deg<<<EB4, 256, 0, stream>>>(dst, degE);
    k_dinv<<<NB, 256, 0, stream>>>(degE, batch, dinv, gcnt);
    k_scan1<<<SCB, 1024, 0, stream>>>(degE, tmp, bsum);
    k_scan2<<<1, 128, 0, stream>>>(bsum, SCB);
    k_scan3<<<NB, 256, 0, stream>>>(tmp, bsum, rowptr, cursor);
    for (int s = 0; s < SWEEPS; s++)
        k_fill<<<EB4, 256, 0, stream>>>(src, dst, cursor, cols, s * SWEEP_W);

    k_h0<<<NHB, 256, 0, stream>>>(x, Win, bin_, h);

    const int XWB = (N_NODES + 63) / 64;             // 1563
    for (int l = 0; l < NLAY; l++) {
        const float* Wl   = convW + (size_t)l * HID * HID;
        const float* bl   = convB + (size_t)l * HID;
        const float* gnWl = gnW + (size_t)l * HID;
        const float* gnBl = gnB + (size_t)l * HID;
        const float* gnSl = gnS + (size_t)l * HID;
        float* S1l = gS1 + (size_t)l * N_GRAPHS * HID;
        float* S2l = gS2 + (size_t)l * N_GRAPHS * HID;

        k_xw<<<XWB, 256, 0, stream>>>(h, Wl, dinv, y);
        k_agg<<<N_NODES / 4, 256, 0, stream>>>(y, rowptr, cols, dinv, bl, batch, c, S1l, S2l);
        k_stats<<<(N_GRAPHS * HID + 255) / 256, 256, 0, stream>>>(S1l, S2l, gcnt, gnSl, gmean, ginv);
        k_update<<<N_NODES * 16 / 256, 256, 0, stream>>>(c, batch, gmean, ginv, gnWl, gnBl, gnSl, h, gemb,
                                                         (l == NLAY - 1) ? 1 : 0);
    }

    k_cls<<<N_GRAPHS, 64, 0, stream>>>(gemb, gcnt, W1, b1, W2, b2, out);
}

// Round 4
// 855.477 us; speedup vs baseline: 1.5651x; 1.3917x over previous
//
#include <hip/hip_runtime.h>
#include <hip/hip_fp16.h>

#define N_NODES 100000
#define N_EDGES 3200000
#define N_GRAPHS 256
#define NODE_DIM 7
#define HID 64
#define NLAY 3
#define EPSV 1e-5f
#define FILL_NS 320   // slices per residue; grid = 8*FILL_NS

static __device__ __forceinline__ void f4add(float4& a, const float4& b) {
    a.x += b.x; a.y += b.y; a.z += b.z; a.w += b.w;
}

// ---------------- graph-structure kernels (run once per call) ----------------

__global__ __launch_bounds__(256) void k_deg(const int* __restrict__ dst, int* __restrict__ degE) {
    int e4 = blockIdx.x * 256 + threadIdx.x;       // N_EDGES/4 threads
    int4 d = ((const int4*)dst)[e4];
    atomicAdd(&degE[d.x], 1);
    atomicAdd(&degE[d.y], 1);
    atomicAdd(&degE[d.z], 1);
    atomicAdd(&degE[d.w], 1);
}

// batch is sorted: per-graph counts via binary search, zero atomics.
__global__ __launch_bounds__(256) void k_gcnt(const int* __restrict__ batch, int* __restrict__ gcnt) {
    __shared__ int start[N_GRAPHS + 1];
    int g = threadIdx.x;
    int lo = 0, hi = N_NODES;
    while (lo < hi) { int mid = (lo + hi) >> 1; if (batch[mid] < g) lo = mid + 1; else hi = mid; }
    start[g] = lo;
    if (g == 0) start[N_GRAPHS] = N_NODES;
    __syncthreads();
    gcnt[g] = start[g + 1] - start[g];
}

__global__ __launch_bounds__(256) void k_dinv(const int* __restrict__ degE, float* __restrict__ dinv) {
    int v = blockIdx.x * 256 + threadIdx.x;
    if (v < N_NODES) dinv[v] = rsqrtf((float)(degE[v] + 1));   // +1 self-loop; always > 0
}

// inclusive scan of degE within 1024-blocks
__global__ __launch_bounds__(1024) void k_scan1(const int* __restrict__ degE, int* __restrict__ tmp,
                                                int* __restrict__ bsum) {
    __shared__ int sh[1024];
    int i = blockIdx.x * 1024 + threadIdx.x;
    int v = (i < N_NODES) ? degE[i] : 0;
    sh[threadIdx.x] = v;
    __syncthreads();
    for (int ofs = 1; ofs < 1024; ofs <<= 1) {
        int t = (threadIdx.x >= (unsigned)ofs) ? sh[threadIdx.x - ofs] : 0;
        __syncthreads();
        sh[threadIdx.x] += t;
        __syncthreads();
    }
    if (i < N_NODES) tmp[i] = sh[threadIdx.x];
    if (threadIdx.x == 1023) bsum[blockIdx.x] = sh[1023];
}

__global__ __launch_bounds__(128) void k_scan2(int* __restrict__ bsum, int nb) {
    __shared__ int sh[128];
    int t = threadIdx.x;
    int v = (t < nb) ? bsum[t] : 0;
    sh[t] = v;
    __syncthreads();
    for (int ofs = 1; ofs < 128; ofs <<= 1) {
        int u = (t >= ofs) ? sh[t - ofs] : 0;
        __syncthreads();
        sh[t] += u;
        __syncthreads();
    }
    if (t < nb) bsum[t] = sh[t] - v;   // exclusive block offsets
}

// rowptr[i+1] = inclusive scan; also seed cursor
__global__ __launch_bounds__(256) void k_scan3(const int* __restrict__ tmp, const int* __restrict__ bsum,
                                               int* __restrict__ rowptr, int* __restrict__ cursor) {
    int i = blockIdx.x * 256 + threadIdx.x;
    if (i < N_NODES) {
        int incl = tmp[i] + bsum[i >> 10];
        rowptr[i + 1] = incl;
        if (i + 1 < N_NODES) cursor[i + 1] = incl;
    }
    if (i == 0) { rowptr[0] = 0; cursor[0] = 0; }
}

// XCD-pinned fill: block residue (bid&7) -> XCD r -> dst octant r.
// All cols/cursor lines of octant r are touched by XCD r only -> full-line
// L2-local accumulation, no cross-XCD partial-line writeback thrash.
__global__ __launch_bounds__(256) void k_fill(const int* __restrict__ src, const int* __restrict__ dst,
                                              int* __restrict__ cursor, int* __restrict__ cols) {
    const int r = blockIdx.x & 7;
    const int slice = blockIdx.x >> 3;
    const int lo = r * (N_NODES / 8), hi = lo + (N_NODES / 8);
    const int NI4 = N_EDGES / 4;
    for (int i = slice * 256 + threadIdx.x; i < NI4; i += FILL_NS * 256) {
        int4 d = ((const int4*)dst)[i];
        int4 s = ((const int4*)src)[i];
        if (d.x >= lo && d.x < hi) cols[atomicAdd(&cursor[d.x], 1)] = s.x;
        if (d.y >= lo && d.y < hi) cols[atomicAdd(&cursor[d.y], 1)] = s.y;
        if (d.z >= lo && d.z < hi) cols[atomicAdd(&cursor[d.z], 1)] = s.z;
        if (d.w >= lo && d.w < hi) cols[atomicAdd(&cursor[d.w], 1)] = s.w;
    }
}

// ---------------- per-layer kernels ----------------

// h0 = x @ Win + bin
__global__ __launch_bounds__(256) void k_h0(const float* __restrict__ x, const float* __restrict__ Win,
                                            const float* __restrict__ b, float* __restrict__ h) {
    int i = blockIdx.x * 256 + threadIdx.x;
    if (i >= N_NODES * HID) return;
    int v = i >> 6, j = i & 63;
    float acc = b[j];
#pragma unroll
    for (int k = 0; k < NODE_DIM; k++) acc += x[v * NODE_DIM + k] * Win[k * HID + j];
    h[i] = acc;
}

// y = fp16( (h @ W) * dinv[:,None] ) ; 64 nodes per block; 4-row register blocking.
__global__ __launch_bounds__(256) void k_xw(const float* __restrict__ h, const float* __restrict__ W,
                                            const float* __restrict__ dinv, __half* __restrict__ y) {
    __shared__ float Ws[HID][HID];
    __shared__ float Hs[64][HID];
    int t = threadIdx.x;
    int nb = blockIdx.x * 64;
#pragma unroll
    for (int it = 0; it < 4; it++) {
        int i = t + it * 256;                 // float4 index, 1024 total
        ((float4*)Ws)[i] = ((const float4*)W)[i];
        int r = i >> 4, c4 = i & 15;
        int node = nb + r;
        float4 hv = make_float4(0.f, 0.f, 0.f, 0.f);
        if (node < N_NODES) hv = ((const float4*)h)[(size_t)node * 16 + c4];
        ((float4*)&Hs[r][0])[c4] = hv;
    }
    __syncthreads();
    int j = t & 63;
    int r0 = t >> 6;          // 0..3
#pragma unroll
    for (int o = 0; o < 4; o++) {
        int ra = r0 + o * 16;                 // rows ra, ra+4, ra+8, ra+12
        float a0 = 0.f, a1 = 0.f, a2 = 0.f, a3 = 0.f;
#pragma unroll
        for (int k4 = 0; k4 < 16; k4++) {
            float4 h0 = ((const float4*)&Hs[ra][0])[k4];
            float4 h1 = ((const float4*)&Hs[ra + 4][0])[k4];
            float4 h2 = ((const float4*)&Hs[ra + 8][0])[k4];
            float4 h3 = ((const float4*)&Hs[ra + 12][0])[k4];
            float w0 = Ws[k4 * 4 + 0][j];
            float w1 = Ws[k4 * 4 + 1][j];
            float w2 = Ws[k4 * 4 + 2][j];
            float w3 = Ws[k4 * 4 + 3][j];
            a0 += h0.x * w0 + h0.y * w1 + h0.z * w2 + h0.w * w3;
            a1 += h1.x * w0 + h1.y * w1 + h1.z * w2 + h1.w * w3;
            a2 += h2.x * w0 + h2.y * w1 + h2.z * w2 + h2.w * w3;
            a3 += h3.x * w0 + h3.y * w1 + h3.z * w2 + h3.w * w3;
        }
        int n0 = nb + ra, n1 = n0 + 4, n2 = n0 + 8, n3 = n0 + 12;
        if (n0 < N_NODES) y[(size_t)n0 * HID + j] = __float2half(a0 * dinv[n0]);
        if (n1 < N_NODES) y[(size_t)n1 * HID + j] = __float2half(a1 * dinv[n1]);
        if (n2 < N_NODES) y[(size_t)n2 * HID + j] = __float2half(a2 * dinv[n2]);
        if (n3 < N_NODES) y[(size_t)n3 * HID + j] = __float2half(a3 * dinv[n3]);
    }
}

// c[v] = dinv[v]*(y[v] + sum_{in-edges} y[s]) + bias ; fused per-graph S1/S2 stats.
// One wave per node. fp16 rows = 128B = 8 lanes x uint4; lane-group q (8 lanes)
// gathers edge e+q -> 1KB/instr covering 8 edges. f32 accumulate.
__global__ __launch_bounds__(256) void k_agg(const __half* __restrict__ y, const int* __restrict__ rowptr,
                                             const int* __restrict__ cols, const float* __restrict__ dinv,
                                             const float* __restrict__ bias, const int* __restrict__ batch,
                                             float* __restrict__ c, float* __restrict__ gS1,
                                             float* __restrict__ gS2) {
    __shared__ float sh1[4][HID];
    __shared__ float sh2[4][HID];
    __shared__ int shg[4];
    const int t = threadIdx.x;
    const int w = t >> 6;          // wave in block
    const int lane = t & 63;
    const int v = blockIdx.x * 4 + w;    // grid covers N_NODES exactly
    const int q = lane >> 3;       // edge group 0..7
    const int f8 = lane & 7;       // uint4 slot within 128B row
    const uint4* __restrict__ y16 = (const uint4*)y;

    float a[8] = {0.f,0.f,0.f,0.f,0.f,0.f,0.f,0.f};
    float b[8] = {0.f,0.f,0.f,0.f,0.f,0.f,0.f,0.f};

    auto unpack_add = [&](float* acc, uint4 u) {
        float2 f0 = __half22float2(*(const __half2*)&u.x);
        float2 f1 = __half22float2(*(const __half2*)&u.y);
        float2 f2 = __half22float2(*(const __half2*)&u.z);
        float2 f3 = __half22float2(*(const __half2*)&u.w);
        acc[0] += f0.x; acc[1] += f0.y;
        acc[2] += f1.x; acc[3] += f1.y;
        acc[4] += f2.x; acc[5] += f2.y;
        acc[6] += f3.x; acc[7] += f3.y;
    };

    if (q == 0) unpack_add(a, y16[(size_t)v * 8 + f8]);     // self-loop
    int e0 = rowptr[v], e1 = rowptr[v + 1];
    int e = e0;
    for (; e + 15 < e1; e += 16) {
        int s0 = cols[e + q];
        int s1 = cols[e + 8 + q];
        uint4 u0 = y16[(size_t)s0 * 8 + f8];
        uint4 u1 = y16[(size_t)s1 * 8 + f8];
        unpack_add(a, u0);
        unpack_add(b, u1);
    }
    if (e + 7 < e1) {
        unpack_add(a, y16[(size_t)cols[e + q] * 8 + f8]);
        e += 8;
    }
    if (e + q < e1) {
        unpack_add(b, y16[(size_t)cols[e + q] * 8 + f8]);
    }
#pragma unroll
    for (int k = 0; k < 8; k++) a[k] += b[k];
    // reduce across the 8 lane-groups (masks 8, 16, 32)
#pragma unroll
    for (int k = 0; k < 8; k++) {
        a[k] += __shfl_xor(a[k], 8);
        a[k] += __shfl_xor(a[k], 16);
        a[k] += __shfl_xor(a[k], 32);
    }

    if (q == 0) {   // lanes 0..7 hold features [f8*8 .. f8*8+7]
        float dv = dinv[v];
        float4 bb0 = ((const float4*)bias)[f8 * 2 + 0];
        float4 bb1 = ((const float4*)bias)[f8 * 2 + 1];
        float cv[8];
        cv[0] = dv * a[0] + bb0.x; cv[1] = dv * a[1] + bb0.y;
        cv[2] = dv * a[2] + bb0.z; cv[3] = dv * a[3] + bb0.w;
        cv[4] = dv * a[4] + bb1.x; cv[5] = dv * a[5] + bb1.y;
        cv[6] = dv * a[6] + bb1.z; cv[7] = dv * a[7] + bb1.w;
        float4* c4 = (float4*)c;
        c4[(size_t)v * 16 + f8 * 2 + 0] = make_float4(cv[0], cv[1], cv[2], cv[3]);
        c4[(size_t)v * 16 + f8 * 2 + 1] = make_float4(cv[4], cv[5], cv[6], cv[7]);
#pragma unroll
        for (int k = 0; k < 8; k++) {
            sh1[w][f8 * 8 + k] = cv[k];
            sh2[w][f8 * 8 + k] = cv[k] * cv[k];
        }
        if (f8 == 0) shg[w] = batch[v];
    }
    __syncthreads();
    if (w == 0) {   // one wave reduces block stats
        int g0 = shg[0];
        bool uni = (shg[1] == g0) && (shg[2] == g0) && (shg[3] == g0);
        if (uni) {
            float s1 = sh1[0][lane] + sh1[1][lane] + sh1[2][lane] + sh1[3][lane];
            float s2 = sh2[0][lane] + sh2[1][lane] + sh2[2][lane] + sh2[3][lane];
            atomicAdd(&gS1[g0 * HID + lane], s1);
            atomicAdd(&gS2[g0 * HID + lane], s2);
        } else {
#pragma unroll
            for (int ww = 0; ww < 4; ww++) {
                atomicAdd(&gS1[shg[ww] * HID + lane], sh1[ww][lane]);
                atomicAdd(&gS2[shg[ww] * HID + lane], sh2[ww][lane]);
            }
        }
    }
}

// per-graph mean / inv-std.  var = S2/cnt - 2*s*m^2 + s^2*m^2
__global__ __launch_bounds__(256) void k_stats(const float* __restrict__ gS1, const float* __restrict__ gS2,
                                               const int* __restrict__ gcnt, const float* __restrict__ gnS_l,
                                               float* __restrict__ gmean, float* __restrict__ ginv) {
    int i = blockIdx.x * 256 + threadIdx.x;
    if (i >= N_GRAPHS * HID) return;
    int g = i >> 6, j = i & 63;
    float cnt = fmaxf((float)gcnt[g], 1.f);
    float m = gS1[i] / cnt;
    float s = gnS_l[j];
    float var = gS2[i] / cnt - 2.f * s * m * m + s * s * m * m;
    gmean[i] = m;
    ginv[i] = rsqrtf(var + EPSV);
}

// h += relu(gnW*(c - s*mean)*invstd + gnB), float4 lanes; 16 nodes/block;
// optional block-reduced graph-emb accumulation.
__global__ __launch_bounds__(256) void k_update(const float* __restrict__ c, const int* __restrict__ batch,
                                                const float* __restrict__ gmean, const float* __restrict__ ginv,
                                                const float* __restrict__ gnW_l, const float* __restrict__ gnB_l,
                                                const float* __restrict__ gnS_l, float* __restrict__ h,
                                                float* __restrict__ gemb, int accum_emb) {
    __shared__ float4 shh[16][16];
    __shared__ int shg[16];
    __shared__ int uniS;
    int t = threadIdx.x;
    int i = blockIdx.x * 256 + t;          // float4 index; grid covers N_NODES*16 exactly
    int v = i >> 4, f = i & 15, r = t >> 4;
    int g = batch[v];
    float4 c4 = ((const float4*)c)[i];
    float4 m4 = ((const float4*)gmean)[g * 16 + f];
    float4 i4 = ((const float4*)ginv)[g * 16 + f];
    float4 w4 = ((const float4*)gnW_l)[f];
    float4 b4 = ((const float4*)gnB_l)[f];
    float4 s4 = ((const float4*)gnS_l)[f];
    float4 h4 = ((const float4*)h)[i];
    float4 hn;
    hn.x = h4.x + fmaxf(w4.x * (c4.x - s4.x * m4.x) * i4.x + b4.x, 0.f);
    hn.y = h4.y + fmaxf(w4.y * (c4.y - s4.y * m4.y) * i4.y + b4.y, 0.f);
    hn.z = h4.z + fmaxf(w4.z * (c4.z - s4.z * m4.z) * i4.z + b4.z, 0.f);
    hn.w = h4.w + fmaxf(w4.w * (c4.w - s4.w * m4.w) * i4.w + b4.w, 0.f);
    ((float4*)h)[i] = hn;
    if (accum_emb) {
        shh[r][f] = hn;
        if (f == 0) shg[r] = g;
        if (t == 0) uniS = 1;
        __syncthreads();
        if (t < 15 && shg[t + 1] != shg[0]) uniS = 0;
        __syncthreads();
        if (uniS) {
            if (t < 128) f4add(shh[t >> 4][t & 15], shh[(t >> 4) + 8][t & 15]);
            __syncthreads();
            if (t < 64) f4add(shh[t >> 4][t & 15], shh[(t >> 4) + 4][t & 15]);
            __syncthreads();
            if (t < 32) f4add(shh[t >> 4][t & 15], shh[(t >> 4) + 2][t & 15]);
            __syncthreads();
            if (t < 16) {
                f4add(shh[0][t], shh[1][t]);
                float4 s = shh[0][t];
                int g0 = shg[0];
                atomicAdd(&gemb[g0 * HID + t * 4 + 0], s.x);
                atomicAdd(&gemb[g0 * HID + t * 4 + 1], s.y);
                atomicAdd(&gemb[g0 * HID + t * 4 + 2], s.z);
                atomicAdd(&gemb[g0 * HID + t * 4 + 3], s.w);
            }
        } else if (t < 16) {
#pragma unroll
            for (int rr = 0; rr < 16; rr++) {
                float4 s = shh[rr][t];
                int gg = shg[rr];
                atomicAdd(&gemb[gg * HID + t * 4 + 0], s.x);
                atomicAdd(&gemb[gg * HID + t * 4 + 1], s.y);
                atomicAdd(&gemb[gg * HID + t * 4 + 2], s.z);
                atomicAdd(&gemb[gg * HID + t * 4 + 3], s.w);
            }
        }
    }
}

// classifier head: emb = gemb/cnt ; z = relu(emb@W1+b1) ; out = z@W2+b2
__global__ __launch_bounds__(64) void k_cls(const float* __restrict__ gemb, const int* __restrict__ gcnt,
                                            const float* __restrict__ W1, const float* __restrict__ b1,
                                            const float* __restrict__ W2, const float* __restrict__ b2,
                                            float* __restrict__ out) {
    __shared__ float emb[HID];
    __shared__ float z[HID];
    int g = blockIdx.x, j = threadIdx.x;
    float cnt = fmaxf((float)gcnt[g], 1.f);
    emb[j] = gemb[g * HID + j] / cnt;
    __syncthreads();
    float acc = b1[j];
    for (int k = 0; k < HID; k++) acc += emb[k] * W1[k * HID + j];
    z[j] = fmaxf(acc, 0.f);
    __syncthreads();
    if (j < 2) {
        float o = b2[j];
        for (int k = 0; k < HID; k++) o += z[k] * W2[k * 2 + j];
        out[g * 2 + j] = o;
    }
}

extern "C" void kernel_launch(void* const* d_in, const int* in_sizes, int n_in,
                              void* d_out, int out_size, void* d_ws, size_t ws_size,
                              hipStream_t stream) {
    const float* x     = (const float*)d_in[0];
    const int*   ei    = (const int*)d_in[1];
    const int*   src   = ei;
    const int*   dst   = ei + N_EDGES;
    const int*   batch = (const int*)d_in[2];
    const float* Win   = (const float*)d_in[3];
    const float* bin_  = (const float*)d_in[4];
    const float* convW = (const float*)d_in[5];
    const float* convB = (const float*)d_in[6];
    const float* gnW   = (const float*)d_in[7];
    const float* gnB   = (const float*)d_in[8];
    const float* gnS   = (const float*)d_in[9];
    const float* W1    = (const float*)d_in[10];
    const float* b1    = (const float*)d_in[11];
    const float* W2    = (const float*)d_in[12];
    const float* b2    = (const float*)d_in[13];
    float* out = (float*)d_out;

    char* ws = (char*)d_ws;
    size_t off = 0;
    auto alloc = [&](size_t bytes) -> void* {
        void* p = ws + off;
        off = (off + bytes + 255) & ~(size_t)255;
        return p;
    };
    // ---- zeroed region (one memset) ----
    int*   degE   = (int*)alloc((size_t)N_NODES * 4);
    float* gS1    = (float*)alloc((size_t)NLAY * N_GRAPHS * HID * 4);
    float* gS2    = (float*)alloc((size_t)NLAY * N_GRAPHS * HID * 4);
    float* gemb   = (float*)alloc((size_t)N_GRAPHS * HID * 4);
    size_t zeroBytes = off;
    // ---- rest ----
    int*   gcnt   = (int*)alloc((size_t)N_GRAPHS * 4);
    int*   cursor = (int*)alloc((size_t)N_NODES * 4);
    float* dinv   = (float*)alloc((size_t)N_NODES * 4);
    int*   rowptr = (int*)alloc((size_t)(N_NODES + 1) * 4);
    int*   tmp    = (int*)alloc((size_t)N_NODES * 4);
    int*   bsum   = (int*)alloc(128 * 4);
    float* h      = (float*)alloc((size_t)N_NODES * HID * 4);
    __half* y     = (__half*)alloc((size_t)N_NODES * HID * 2);
    float* c      = (float*)alloc((size_t)N_NODES * HID * 4);
    int*   cols   = (int*)alloc((size_t)N_EDGES * 4);
    float* gmean  = (float*)alloc((size_t)N_GRAPHS * HID * 4);
    float* ginv   = (float*)alloc((size_t)N_GRAPHS * HID * 4);
    (void)ws_size; (void)in_sizes; (void)n_in; (void)out_size;

    hipMemsetAsync(d_ws, 0, zeroBytes, stream);

    const int EB4 = N_EDGES / 4 / 256;               // 3125
    const int NB = (N_NODES + 255) / 256;            // 391
    const int NHB = (N_NODES * HID + 255) / 256;     // 25000
    const int SCB = (N_NODES + 1023) / 1024;         // 98

    k_deg<<<EB4, 256, 0, stream>>>(dst, degE);
    k_gcnt<<<1, 256, 0, stream>>>(batch, gcnt);
    k_dinv<<<NB, 256, 0, stream>>>(degE, dinv);
    k_scan1<<<SCB, 1024, 0, stream>>>(degE, tmp, bsum);
    k_scan2<<<1, 128, 0, stream>>>(bsum, SCB);
    k_scan3<<<NB, 256, 0, stream>>>(tmp, bsum, rowptr, cursor);
    k_fill<<<8 * FILL_NS, 256, 0, stream>>>(src, dst, cursor, cols);

    k_h0<<<NHB, 256, 0, stream>>>(x, Win, bin_, h);

    const int XWB = (N_NODES + 63) / 64;             // 1563
    for (int l = 0; l < NLAY; l++) {
        const float* Wl   = convW + (size_t)l * HID * HID;
        const float* bl   = convB + (size_t)l * HID;
        const float* gnWl = gnW + (size_t)l * HID;
        const float* gnBl = gnB + (size_t)l * HID;
        const float* gnSl = gnS + (size_t)l * HID;
        float* S1l = gS1 + (size_t)l * N_GRAPHS * HID;
        float* S2l = gS2 + (size_t)l * N_GRAPHS * HID;

        k_xw<<<XWB, 256, 0, stream>>>(h, Wl, dinv, y);
        k_agg<<<N_NODES / 4, 256, 0, stream>>>(y, rowptr, cols, dinv, bl, batch, c, S1l, S2l);
        k_stats<<<(N_GRAPHS * HID + 255) / 256, 256, 0, stream>>>(S1l, S2l, gcnt, gnSl, gmean, ginv);
        k_update<<<N_NODES * 16 / 256, 256, 0, stream>>>(c, batch, gmean, ginv, gnWl, gnBl, gnSl, h, gemb,
                                                         (l == NLAY - 1) ? 1 : 0);
    }

    k_cls<<<N_GRAPHS, 64, 0, stream>>>(gemb, gcnt, W1, b1, W2, b2, out);
}